// Round 7
// baseline (182.929 us; speedup 1.0000x reference)
//
#include <hip/hip_runtime.h>
#include <stdint.h>

typedef signed char i8;
typedef __attribute__((ext_vector_type(4))) float f32x4;
typedef __attribute__((ext_vector_type(4))) int i32x4;

#define XSCALE 32.0f
#define INV_XSCALE (1.0f / 32.0f)

// ---------------- conversion kernels ----------------

__device__ __forceinline__ int q8(float f) {
  float s = rintf(f * XSCALE);
  s = fminf(fmaxf(s, -127.0f), 127.0f);
  return ((int)s) & 0xff;
}

// x fp32 -> i8 (scale 32), 16 elems/thread
__global__ __launch_bounds__(256) void cvt_x_kernel(const float* __restrict__ x,
                                                    i32x4* __restrict__ o, int n16) {
  int i = blockIdx.x * blockDim.x + threadIdx.x;
  int stride = gridDim.x * blockDim.x;
  for (; i < n16; i += stride) {
    const f32x4* p = (const f32x4*)x + (size_t)i * 4;
    f32x4 v0 = p[0], v1 = p[1], v2 = p[2], v3 = p[3];
    i32x4 r;
    r[0] = q8(v0[0]) | (q8(v0[1]) << 8) | (q8(v0[2]) << 16) | (q8(v0[3]) << 24);
    r[1] = q8(v1[0]) | (q8(v1[1]) << 8) | (q8(v1[2]) << 16) | (q8(v1[3]) << 24);
    r[2] = q8(v2[0]) | (q8(v2[1]) << 8) | (q8(v2[2]) << 16) | (q8(v2[3]) << 24);
    r[3] = q8(v3[0]) | (q8(v3[1]) << 8) | (q8(v3[2]) << 16) | (q8(v3[3]) << 24);
    o[i] = r;
  }
}

__device__ __forceinline__ int sg8(float f) {
  return (f > 0.0f ? 1 : (f < 0.0f ? -1 : 0)) & 0xff;
}

// w fp32 -> sign i8 (+1/-1/0), 16 elems/thread
__global__ __launch_bounds__(256) void cvt_w_kernel(const float* __restrict__ w,
                                                    i32x4* __restrict__ o, int n16) {
  int i = blockIdx.x * blockDim.x + threadIdx.x;
  int stride = gridDim.x * blockDim.x;
  for (; i < n16; i += stride) {
    const f32x4* p = (const f32x4*)w + (size_t)i * 4;
    f32x4 v0 = p[0], v1 = p[1], v2 = p[2], v3 = p[3];
    i32x4 r;
    r[0] = sg8(v0[0]) | (sg8(v0[1]) << 8) | (sg8(v0[2]) << 16) | (sg8(v0[3]) << 24);
    r[1] = sg8(v1[0]) | (sg8(v1[1]) << 8) | (sg8(v1[2]) << 16) | (sg8(v1[3]) << 24);
    r[2] = sg8(v2[0]) | (sg8(v2[1]) << 8) | (sg8(v2[2]) << 16) | (sg8(v2[3]) << 24);
    r[3] = sg8(v3[0]) | (sg8(v3[1]) << 8) | (sg8(v3[2]) << 16) | (sg8(v3[3]) << 24);
    o[i] = r;
  }
}

// ---------------- 128x256 i8 MFMA GEMM, 2 independent blocks/CU -----------
// r20: break the CU-wide convoy with INDEPENDENT BARRIER GROUPS. Additive
// budget (r12-r19, all ~165us): per K-tile/CU = MFMA 1306 + LDS-read 768 +
// LDS-stage-write 256 + sync ~600 ~= 3000cyc measured. Every variant kept
// all resident waves in ONE barrier group: at each phase all waves issue
// reads together, the port drains them together, all enter MFMA together
// -- pipes alternate, times ADD. r19's free 12.6M bank conflicts and the
// r15 occupancy null both confirm no single pipe is the wall; the convoy
// is. m114: independent waves overlap pipes (max), barrier-synced don't.
// Fix: 2 co-resident 512-thread blocks per CU (block tile 128x256, 8
// waves x 64x64/wave): two free-running schedules; block A's MFMA covers
// block B's read-drain. Per-block phase is deliberately SERIAL (stage 3
// units, 8 ds_reads, lgkm0, 16 MFMA, counted VMCNT3, 1 BAR) -- overlap
// comes from the sibling block, not intra-wave scheduling.
// Budget: regs ~60 VGPR + 64 AGPR <= 128 -> 4 waves/SIMD (2 blocks);
// LDS 3 bufs x (A 8KB + B 16KB) = 72KB/block -> 2 blocks = 144KB <= 160.

__device__ __forceinline__ void load_lds16(const void* g, void* l) {
  __builtin_amdgcn_global_load_lds(
      (const __attribute__((address_space(1))) void*)g,
      (__attribute__((address_space(3))) void*)l,
      16, 0, 0);
}

// stage one 8KB unit (128 rows x 64 cols i8); u=0,1 for 256-row tiles.
__device__ __forceinline__ void stage_unit(const i8* __restrict__ Gp, int K, int k0,
                                           i8* __restrict__ Tlds, int u, int wave,
                                           int lane) {
  const int base = u * 8192 + wave * 1024;        // physical byte base (wave-uniform)
  const int PA = base + lane * 16;                // this lane's physical bytes
  const int L = PA ^ (((PA >> 7) & 3) << 4);      // logical bytes (involution)
  const int r = L >> 6;                           // tile row (64 i8 per row)
  const int c = L & 63;                           // tile col (16-aligned)
  load_lds16(Gp + (size_t)r * K + k0 + c, Tlds + base);
}

#define BAR __builtin_amdgcn_s_barrier()
#define SGB __builtin_amdgcn_sched_barrier(0)
#define WAITL0 asm volatile("s_waitcnt lgkmcnt(0)" ::: "memory")
#define VMCNT3 asm volatile("s_waitcnt vmcnt(3)" ::: "memory")
#define VMCNT0 asm volatile("s_waitcnt vmcnt(0)" ::: "memory")

#define MFMA16                                                                  \
  __builtin_amdgcn_s_setprio(1);                                                \
  _Pragma("unroll") for (int mi = 0; mi < 4; ++mi)                              \
  _Pragma("unroll") for (int ni = 0; ni < 4; ++ni)                              \
    acc[mi][ni] = __builtin_amdgcn_mfma_i32_16x16x64_i8(                        \
        Af[mi], Bf[ni], acc[mi][ni], 0, 0, 0);                                  \
  __builtin_amdgcn_s_setprio(0);

// Buffer layout: A [128][64] at +0 (8KB), B [256][64] at +8192 (16KB).
// PR = buf[t%3] (read), PS = buf[(t+2)%3] (stage target for K-tile t+2).
// vmcnt: at entry, stage(t+1)'s 3 units outstanding; we issue stage(t+2)
// -> VMCNT3 retires exactly stage(t+1); BAR publishes it for tile t+1.
// Overwrite safety: stage(t+2) hits buf[(t+2)%3]=buf[(t-1)%3], whose
// reads (tile t-1) retired at tile t-1's WAITL0 before its BAR.
#define DO_TILE(t, PR, PS)                                                      \
  if ((t) < NT) {                                                               \
    if ((t) + 2 < NT) {                                                         \
      stage_unit(GA, K, ((t) + 2) * 64, (PS), 0, wave, lane);                   \
      stage_unit(GB, K, ((t) + 2) * 64, (PS) + 8192, 0, wave, lane);            \
      stage_unit(GB, K, ((t) + 2) * 64, (PS) + 8192, 1, wave, lane);            \
    }                                                                           \
    _Pragma("unroll") for (int mi = 0; mi < 4; ++mi)                            \
      Af[mi] = *(const i32x4*)((PR) + abase + mi * 1024);                       \
    _Pragma("unroll") for (int ni = 0; ni < 4; ++ni)                            \
      Bf[ni] = *(const i32x4*)((PR) + 8192 + bbase + ni * 1024);                \
    WAITL0; SGB;                                                                \
    MFMA16;                                                                     \
    SGB;                                                                        \
    if ((t) + 2 < NT) { VMCNT3; }                                               \
    else if ((t) + 1 < NT) { VMCNT0; }                                          \
    BAR;                                                                        \
  }

__global__ __launch_bounds__(512, 4) void bingemm128_kernel(
    const i8* __restrict__ A,      // [M][K] i8 (x * 32)
    const i8* __restrict__ B,      // [N][K] i8 sign
    const float* __restrict__ alpha,
    const float* __restrict__ bias,
    float* __restrict__ C,         // [M][N] fp32
    int M, int N, int K) {
  __shared__ i8 SM[3][24576];      // 3 x (A 8KB + B 16KB) = 72 KB

  const int tid = threadIdx.x;
  const int lane = tid & 63;
  const int wave = tid >> 6;  // 0..7
  const int wm = wave >> 2;   // 0..1 (64-row slab)
  const int wn = wave & 3;    // 0..3 (64-col slab)
  const int l15 = lane & 15;

  // XCD-aware swizzle (grid divisible by 8 -> simple bijection)
  const int nwg = gridDim.x;
  const int wg = blockIdx.x;
  const int wgid = ((nwg & 7) == 0) ? ((wg & 7) * (nwg >> 3) + (wg >> 3)) : wg;

  const int nbn = N / 256;
  const int tm = wgid / nbn;
  const int tn = wgid % nbn;

  const i8* GA = A + (size_t)tm * 128 * K;
  const i8* GB = B + (size_t)tn * 256 * K;

  // swizzled ds_read byte offsets (row stride 64B, granule 16B):
  // phys k-part = (kq ^ ((row>>1)&3))<<4, (row>>1)&3 == (l15>>1)&3
  const int kq = lane >> 4;                 // 0..3
  const int kph = ((kq ^ ((l15 >> 1) & 3)) << 4);
  const int abase = (wm * 64 + l15) * 64 + kph;    // + mi*1024 (16 rows)
  const int bbase = (wn * 64 + l15) * 64 + kph;    // + ni*1024

  i32x4 acc[4][4];
#pragma unroll
  for (int i = 0; i < 4; ++i)
#pragma unroll
    for (int j = 0; j < 4; ++j)
#pragma unroll
      for (int q = 0; q < 4; ++q) acc[i][j][q] = 0;

  const int NT = K / 64;

  i32x4 Af[4], Bf[4];

  i8* const q0 = &SM[0][0];
  i8* const q1 = &SM[1][0];
  i8* const q2 = &SM[2][0];

  // ---- prologue: stage t0->buf0, t1->buf1; retire t0 ----
  stage_unit(GA, K, 0, q0, 0, wave, lane);
  stage_unit(GB, K, 0, q0 + 8192, 0, wave, lane);
  stage_unit(GB, K, 0, q0 + 8192, 1, wave, lane);
  stage_unit(GA, K, 64, q1, 0, wave, lane);
  stage_unit(GB, K, 64, q1 + 8192, 0, wave, lane);
  stage_unit(GB, K, 64, q1 + 8192, 1, wave, lane);
  VMCNT3;   // t0's 3 units done; t1's 3 in flight
  BAR;

  for (int t = 0; t < NT; t += 3) {
    DO_TILE(t,     q0, q2);
    DO_TILE(t + 1, q1, q0);
    DO_TILE(t + 2, q2, q1);
  }

  // ---- epilogue: C = acc * alpha[col]/32 + bias[col] (nontemporal) ----
  const int r0 = tm * 128 + wm * 64 + ((lane >> 4) << 2);
  const int c0 = tn * 256 + wn * 64 + l15;
#pragma unroll
  for (int an = 0; an < 4; ++an) {
    const int col = c0 + an * 16;
    const float al = alpha[col] * INV_XSCALE;
    const float bi = bias[col];
#pragma unroll
    for (int am = 0; am < 4; ++am) {
#pragma unroll
      for (int j = 0; j < 4; ++j) {
        __builtin_nontemporal_store((float)acc[am][an][j] * al + bi,
                                    &C[(size_t)(r0 + am * 16 + j) * N + col]);
      }
    }
  }
}

// ---------------- fallback (insurance: ws too small / bad dims) ----------------

__global__ __launch_bounds__(256) void naive_kernel(
    const float* __restrict__ x, const float* __restrict__ w,
    const float* __restrict__ alpha, const float* __restrict__ bias,
    float* __restrict__ out, int M, int N, int K) {
  long idx = (long)blockIdx.x * blockDim.x + threadIdx.x;
  const long total = (long)M * N;
  const long stride = (long)gridDim.x * blockDim.x;
  for (; idx < total; idx += stride) {
    const int m = (int)(idx / N);
    const int n = (int)(idx % N);
    const float* xr = x + (size_t)m * K;
    const float* wr = w + (size_t)n * K;
    float s = 0.0f;
    for (int k = 0; k < K; ++k) {
      const float wv = wr[k];
      const float sg = (wv > 0.0f) ? 1.0f : ((wv < 0.0f) ? -1.0f : 0.0f);
      s += xr[k] * sg;
    }
    out[idx] = s * alpha[n] + bias[n];
  }
}

// ---------------- launcher ----------------

extern "C" void kernel_launch(void* const* d_in, const int* in_sizes, int n_in,
                              void* d_out, int out_size, void* d_ws, size_t ws_size,
                              hipStream_t stream) {
  const float* x = (const float*)d_in[0];
  const float* w = (const float*)d_in[1];
  const float* alpha = (const float*)d_in[2];
  const float* bias = (const float*)d_in[3];
  float* out = (float*)d_out;

  const int OUT = in_sizes[3];                // bias length
  const int IN = in_sizes[1] / OUT;           // weight is [OUT][IN]
  const int M = in_sizes[0] / IN;             // x is [B][IN]
  const int N = OUT, K = IN;

  const size_t xbytes = (size_t)M * K;        // i8
  const size_t wbytes = (size_t)N * K;        // i8
  // guards assume NT = K/64 >= 3.
  const bool ok = (ws_size >= xbytes + wbytes) &&
                  (M % 128 == 0) && (N % 256 == 0) && (K % 64 == 0) &&
                  (K >= 192);

  if (!ok) {
    naive_kernel<<<2048, 256, 0, stream>>>(x, w, alpha, bias, out, M, N, K);
    return;
  }

  i8* xb = (i8*)d_ws;
  i8* wb = xb + xbytes;

  cvt_x_kernel<<<2048, 256, 0, stream>>>(x, (i32x4*)xb, (int)((size_t)M * K / 16));
  cvt_w_kernel<<<2048, 256, 0, stream>>>(w, (i32x4*)wb, (int)((size_t)N * K / 16));

  const int grid = (M / 128) * (N / 256);
  bingemm128_kernel<<<grid, 512, 0, stream>>>(xb, wb, alpha, bias, out, M, N, K);
}

// Round 8
// 178.226 us; speedup vs baseline: 1.0264x; 1.0264x over previous
//
#include <hip/hip_runtime.h>
#include <stdint.h>

typedef signed char i8;
typedef __attribute__((ext_vector_type(4))) float f32x4;
typedef __attribute__((ext_vector_type(4))) int i32x4;

#define XSCALE 32.0f
#define INV_XSCALE (1.0f / 32.0f)

// ---------------- conversion kernels ----------------

__device__ __forceinline__ int q8(float f) {
  float s = rintf(f * XSCALE);
  s = fminf(fmaxf(s, -127.0f), 127.0f);
  return ((int)s) & 0xff;
}

// x fp32 -> i8 (scale 32), 16 elems/thread
__global__ __launch_bounds__(256) void cvt_x_kernel(const float* __restrict__ x,
                                                    i32x4* __restrict__ o, int n16) {
  int i = blockIdx.x * blockDim.x + threadIdx.x;
  int stride = gridDim.x * blockDim.x;
  for (; i < n16; i += stride) {
    const f32x4* p = (const f32x4*)x + (size_t)i * 4;
    f32x4 v0 = p[0], v1 = p[1], v2 = p[2], v3 = p[3];
    i32x4 r;
    r[0] = q8(v0[0]) | (q8(v0[1]) << 8) | (q8(v0[2]) << 16) | (q8(v0[3]) << 24);
    r[1] = q8(v1[0]) | (q8(v1[1]) << 8) | (q8(v1[2]) << 16) | (q8(v1[3]) << 24);
    r[2] = q8(v2[0]) | (q8(v2[1]) << 8) | (q8(v2[2]) << 16) | (q8(v2[3]) << 24);
    r[3] = q8(v3[0]) | (q8(v3[1]) << 8) | (q8(v3[2]) << 16) | (q8(v3[3]) << 24);
    o[i] = r;
  }
}

__device__ __forceinline__ int sg8(float f) {
  return (f > 0.0f ? 1 : (f < 0.0f ? -1 : 0)) & 0xff;
}

// w fp32 -> sign i8 (+1/-1/0), 16 elems/thread
__global__ __launch_bounds__(256) void cvt_w_kernel(const float* __restrict__ w,
                                                    i32x4* __restrict__ o, int n16) {
  int i = blockIdx.x * blockDim.x + threadIdx.x;
  int stride = gridDim.x * blockDim.x;
  for (; i < n16; i += stride) {
    const f32x4* p = (const f32x4*)w + (size_t)i * 4;
    f32x4 v0 = p[0], v1 = p[1], v2 = p[2], v3 = p[3];
    i32x4 r;
    r[0] = sg8(v0[0]) | (sg8(v0[1]) << 8) | (sg8(v0[2]) << 16) | (sg8(v0[3]) << 24);
    r[1] = sg8(v1[0]) | (sg8(v1[1]) << 8) | (sg8(v1[2]) << 16) | (sg8(v1[3]) << 24);
    r[2] = sg8(v2[0]) | (sg8(v2[1]) << 8) | (sg8(v2[2]) << 16) | (sg8(v2[3]) << 24);
    r[3] = sg8(v3[0]) | (sg8(v3[1]) << 8) | (sg8(v3[2]) << 16) | (sg8(v3[3]) << 24);
    o[i] = r;
  }
}

// ---------------- 256x128 i8 MFMA GEMM, 2 indep 4-wave blocks/CU ----------
// r21 = r20's proven mechanism (independent barrier groups: 165->153.5us,
// the only positive delta in 8 rounds) + fixed geometry. r20 residuals:
// (a) cross-block overlap partial (41% of sum->max gap closed), (b) at
// perfect overlap r20 is LDS-bound: 64x64 wave tiles = 0.5 ds_reads/MFMA,
// 3x read amplification -> LDS 2114 cyc/pair > MFMA 1304. Fix: 4-wave
// blocks (256 thr), block tile 256x128, wave tile 128x64 (0.375 reads/
// MFMA; A-amp x2, B-amp x2 balanced -- the minimum under the 128-reg acc
// constraint). LDS/pair 2114->1730, sum 3414->3034. Regs: acc 128 + frags
// 48 + addr ~ 210 < 256 -> 2 waves/SIMD = ONE wave per block per SIMD;
// intra-block stays serial (stage 6x1KB units, 12 ds_reads, lgkm0,
// 32 MFMA, counted VMCNT6, 1 BAR) -- overlap comes from the sibling block.
// LDS: 3 bufs x (A 16KB + B 8KB) = 72KB/block -> 2 blocks = 144 <= 160.

__device__ __forceinline__ void load_lds16(const void* g, void* l) {
  __builtin_amdgcn_global_load_lds(
      (const __attribute__((address_space(1))) void*)g,
      (__attribute__((address_space(3))) void*)l,
      16, 0, 0);
}

// stage one 4KB unit (64 rows x 64 cols i8) with 4 waves x 1KB.
// Tile is [R][64] row-major at Tlds; u indexes 4KB units (A: u=0..3, B: 0..1).
__device__ __forceinline__ void stage_u4(const i8* __restrict__ Gp, int K, int k0,
                                         i8* __restrict__ Tlds, int u, int wave,
                                         int lane) {
  const int base = u * 4096 + wave * 1024;        // physical byte base (wave-uniform)
  const int PA = base + lane * 16;                // this lane's physical bytes
  const int L = PA ^ (((PA >> 7) & 3) << 4);      // logical bytes (involution)
  const int r = L >> 6;                           // tile row (64 i8 per row)
  const int c = L & 63;                           // tile col (16-aligned)
  load_lds16(Gp + (size_t)r * K + k0 + c, Tlds + base);
}

#define BAR __builtin_amdgcn_s_barrier()
#define SGB __builtin_amdgcn_sched_barrier(0)
#define WAITL0 asm volatile("s_waitcnt lgkmcnt(0)" ::: "memory")
#define VMCNT6 asm volatile("s_waitcnt vmcnt(6)" ::: "memory")
#define VMCNT0 asm volatile("s_waitcnt vmcnt(0)" ::: "memory")

#define MFMA32                                                                  \
  __builtin_amdgcn_s_setprio(1);                                                \
  _Pragma("unroll") for (int mi = 0; mi < 8; ++mi)                              \
  _Pragma("unroll") for (int ni = 0; ni < 4; ++ni)                              \
    acc[mi][ni] = __builtin_amdgcn_mfma_i32_16x16x64_i8(                        \
        Af[mi], Bf[ni], acc[mi][ni], 0, 0, 0);                                  \
  __builtin_amdgcn_s_setprio(0);

// Buffer layout: A [256][64] at +0 (16KB), B [128][64] at +16384 (8KB).
// PR = buf[t%3] (read), PS = buf[(t+2)%3] (stage target for tile t+2).
// vmcnt: entry has stage(t+1)'s 6 outstanding; issue stage(t+2)'s 6 ->
// VMCNT6 retires exactly stage(t+1); BAR publishes it for tile t+1.
// Overwrite safety: stage(t+2) hits buf[(t-1)%3], whose reads (tile t-1)
// retired at tile t-1's WAITL0 before its BAR.
#define DO_TILE(t, PR, PS)                                                      \
  if ((t) < NT) {                                                               \
    if ((t) + 2 < NT) {                                                         \
      const int k2 = ((t) + 2) * 64;                                            \
      stage_u4(GA, K, k2, (PS), 0, wave, lane);                                 \
      stage_u4(GA, K, k2, (PS), 1, wave, lane);                                 \
      stage_u4(GA, K, k2, (PS), 2, wave, lane);                                 \
      stage_u4(GA, K, k2, (PS), 3, wave, lane);                                 \
      stage_u4(GB, K, k2, (PS) + 16384, 0, wave, lane);                         \
      stage_u4(GB, K, k2, (PS) + 16384, 1, wave, lane);                         \
    }                                                                           \
    _Pragma("unroll") for (int mi = 0; mi < 8; ++mi)                            \
      Af[mi] = *(const i32x4*)((PR) + abase + mi * 1024);                       \
    _Pragma("unroll") for (int ni = 0; ni < 4; ++ni)                            \
      Bf[ni] = *(const i32x4*)((PR) + 16384 + bbase + ni * 1024);               \
    WAITL0; SGB;                                                                \
    MFMA32;                                                                     \
    SGB;                                                                        \
    if ((t) + 2 < NT) { VMCNT6; }                                               \
    else if ((t) + 1 < NT) { VMCNT0; }                                          \
    BAR;                                                                        \
  }

__global__ __launch_bounds__(256, 2) void bingemm128_kernel(
    const i8* __restrict__ A,      // [M][K] i8 (x * 32)
    const i8* __restrict__ B,      // [N][K] i8 sign
    const float* __restrict__ alpha,
    const float* __restrict__ bias,
    float* __restrict__ C,         // [M][N] fp32
    int M, int N, int K) {
  __shared__ i8 SM[3][24576];      // 3 x (A 16KB + B 8KB) = 72 KB

  const int tid = threadIdx.x;
  const int lane = tid & 63;
  const int wave = tid >> 6;  // 0..3
  const int wm = wave >> 1;   // 0..1 (128-row slab)
  const int wn = wave & 1;    // 0..1 (64-col slab)
  const int l15 = lane & 15;

  // XCD-aware swizzle (grid divisible by 8 -> simple bijection)
  const int nwg = gridDim.x;
  const int wg = blockIdx.x;
  const int wgid = ((nwg & 7) == 0) ? ((wg & 7) * (nwg >> 3) + (wg >> 3)) : wg;

  const int nbn = N / 128;
  const int tm = wgid / nbn;
  const int tn = wgid % nbn;

  const i8* GA = A + (size_t)tm * 256 * K;
  const i8* GB = B + (size_t)tn * 128 * K;

  // swizzled ds_read byte offsets (row stride 64B, granule 16B):
  // phys k-part = (kq ^ ((row>>1)&3))<<4, (row>>1)&3 == (l15>>1)&3
  const int kq = lane >> 4;                 // 0..3
  const int kph = ((kq ^ ((l15 >> 1) & 3)) << 4);
  const int abase = (wm * 128 + l15) * 64 + kph;   // + mi*1024 (16 rows)
  const int bbase = (wn * 64 + l15) * 64 + kph;    // + ni*1024

  i32x4 acc[8][4];
#pragma unroll
  for (int i = 0; i < 8; ++i)
#pragma unroll
    for (int j = 0; j < 4; ++j)
#pragma unroll
      for (int q = 0; q < 4; ++q) acc[i][j][q] = 0;

  const int NT = K / 64;

  i32x4 Af[8], Bf[4];

  i8* const q0 = &SM[0][0];
  i8* const q1 = &SM[1][0];
  i8* const q2 = &SM[2][0];

  // ---- prologue: stage t0->buf0, t1->buf1; retire t0 ----
  stage_u4(GA, K, 0, q0, 0, wave, lane);
  stage_u4(GA, K, 0, q0, 1, wave, lane);
  stage_u4(GA, K, 0, q0, 2, wave, lane);
  stage_u4(GA, K, 0, q0, 3, wave, lane);
  stage_u4(GB, K, 0, q0 + 16384, 0, wave, lane);
  stage_u4(GB, K, 0, q0 + 16384, 1, wave, lane);
  stage_u4(GA, K, 64, q1, 0, wave, lane);
  stage_u4(GA, K, 64, q1, 1, wave, lane);
  stage_u4(GA, K, 64, q1, 2, wave, lane);
  stage_u4(GA, K, 64, q1, 3, wave, lane);
  stage_u4(GB, K, 64, q1 + 16384, 0, wave, lane);
  stage_u4(GB, K, 64, q1 + 16384, 1, wave, lane);
  VMCNT6;   // t0's 6 units done; t1's 6 in flight
  BAR;

  for (int t = 0; t < NT; t += 3) {
    DO_TILE(t,     q0, q2);
    DO_TILE(t + 1, q1, q0);
    DO_TILE(t + 2, q2, q1);
  }

  // ---- epilogue: C = acc * alpha[col]/32 + bias[col] (nontemporal) ----
  const int r0 = tm * 256 + wm * 128 + ((lane >> 4) << 2);
  const int c0 = tn * 128 + wn * 64 + l15;
#pragma unroll
  for (int an = 0; an < 4; ++an) {
    const int col = c0 + an * 16;
    const float al = alpha[col] * INV_XSCALE;
    const float bi = bias[col];
#pragma unroll
    for (int am = 0; am < 8; ++am) {
#pragma unroll
      for (int j = 0; j < 4; ++j) {
        __builtin_nontemporal_store((float)acc[am][an][j] * al + bi,
                                    &C[(size_t)(r0 + am * 16 + j) * N + col]);
      }
    }
  }
}

// ---------------- fallback (insurance: ws too small / bad dims) ----------------

__global__ __launch_bounds__(256) void naive_kernel(
    const float* __restrict__ x, const float* __restrict__ w,
    const float* __restrict__ alpha, const float* __restrict__ bias,
    float* __restrict__ out, int M, int N, int K) {
  long idx = (long)blockIdx.x * blockDim.x + threadIdx.x;
  const long total = (long)M * N;
  const long stride = (long)gridDim.x * blockDim.x;
  for (; idx < total; idx += stride) {
    const int m = (int)(idx / N);
    const int n = (int)(idx % N);
    const float* xr = x + (size_t)m * K;
    const float* wr = w + (size_t)n * K;
    float s = 0.0f;
    for (int k = 0; k < K; ++k) {
      const float wv = wr[k];
      const float sg = (wv > 0.0f) ? 1.0f : ((wv < 0.0f) ? -1.0f : 0.0f);
      s += xr[k] * sg;
    }
    out[idx] = s * alpha[n] + bias[n];
  }
}

// ---------------- launcher ----------------

extern "C" void kernel_launch(void* const* d_in, const int* in_sizes, int n_in,
                              void* d_out, int out_size, void* d_ws, size_t ws_size,
                              hipStream_t stream) {
  const float* x = (const float*)d_in[0];
  const float* w = (const float*)d_in[1];
  const float* alpha = (const float*)d_in[2];
  const float* bias = (const float*)d_in[3];
  float* out = (float*)d_out;

  const int OUT = in_sizes[3];                // bias length
  const int IN = in_sizes[1] / OUT;           // weight is [OUT][IN]
  const int M = in_sizes[0] / IN;             // x is [B][IN]
  const int N = OUT, K = IN;

  const size_t xbytes = (size_t)M * K;        // i8
  const size_t wbytes = (size_t)N * K;        // i8
  // guards assume NT = K/64 >= 3.
  const bool ok = (ws_size >= xbytes + wbytes) &&
                  (M % 256 == 0) && (N % 128 == 0) && (K % 64 == 0) &&
                  (K >= 192);

  if (!ok) {
    naive_kernel<<<2048, 256, 0, stream>>>(x, w, alpha, bias, out, M, N, K);
    return;
  }

  i8* xb = (i8*)d_ws;
  i8* wb = xb + xbytes;

  cvt_x_kernel<<<2048, 256, 0, stream>>>(x, (i32x4*)xb, (int)((size_t)M * K / 16));
  cvt_w_kernel<<<2048, 256, 0, stream>>>(w, (i32x4*)wb, (int)((size_t)N * K / 16));

  const int grid = (M / 256) * (N / 128);
  bingemm128_kernel<<<grid, 256, 0, stream>>>(xb, wb, alpha, bias, out, M, N, K);
}